// Round 3
// baseline (608.634 us; speedup 1.0000x reference)
//
#include <hip/hip_runtime.h>
#include <hip/hip_bf16.h>
#include <stdint.h>

#define DEV_INLINE __device__ __forceinline__

typedef __attribute__((ext_vector_type(4))) float f32x4;
typedef __attribute__((ext_vector_type(16))) float f32x16;
typedef __attribute__((ext_vector_type(8))) short short8;

static constexpr int S_LEN = 2048;
static constexpr int DM = 1024;
static constexpr int NH = 16;
static constexpr int DK = 64;
static constexpr int BATCH = 4;
static constexpr int M_TOT = BATCH * S_LEN;  // 8192

DEV_INLINE unsigned short bf_round(float x) {
  unsigned u = __builtin_bit_cast(unsigned, x);
  u += 0x7fffu + ((u >> 16) & 1u);
  return (unsigned short)(u >> 16);
}

// ---------------- fp32 -> bf16 convert, all 5 tensors in one dispatch ----------------
struct CvtArgs {
  const float* in[5];
  unsigned short* out[5];
};
// X: 4096 blocks (8192*1024/2048), each weight: 512 blocks (1024*1024/2048)
__global__ __launch_bounds__(256) void cvt_all(CvtArgs a) {
  int bid = blockIdx.x;
  int which, base;
  if (bid < 4096) { which = 0; base = bid; }
  else { int r = bid - 4096; which = 1 + (r >> 9); base = r & 511; }
  const float* __restrict__ in = a.in[which];
  unsigned short* __restrict__ out = a.out[which];
  long i = ((long)base * 256 + threadIdx.x) * 8;
  float4 va = *reinterpret_cast<const float4*>(in + i);
  float4 vb = *reinterpret_cast<const float4*>(in + i + 4);
  union { unsigned short u[8]; uint4 v; } pk;
  pk.u[0] = bf_round(va.x); pk.u[1] = bf_round(va.y);
  pk.u[2] = bf_round(va.z); pk.u[3] = bf_round(va.w);
  pk.u[4] = bf_round(vb.x); pk.u[5] = bf_round(vb.y);
  pk.u[6] = bf_round(vb.z); pk.u[7] = bf_round(vb.w);
  *reinterpret_cast<uint4*>(out + i) = pk.v;
}

// ---------------- async global->LDS 16B ----------------
DEV_INLINE void gload_lds16(const unsigned short* g, unsigned short* l) {
  __builtin_amdgcn_global_load_lds(
      (const __attribute__((address_space(1))) unsigned int*)g,
      (__attribute__((address_space(3))) unsigned int*)l,
      16, 0, 0);
}

// ---------------- GEMM: C[m][n] = sum_k A[m,k] * W[n,k] + bias[n] ----------------
// m97 structure: 128x128 tile, BK=32, 4 waves (2x2), 4x4 16x16x32 frags per wave.
// MODE 0: Q epilogue (scale 1/8, bf16 -> [BH][S][DK])
// MODE 1: K epilogue (bf16 -> [BH][S][DK])
// MODE 2: V epilogue (bf16 -> transposed [BH][DK][S])
// MODE 3: out epilogue (fp32 -> [M][N])
template <int MODE>
__global__ __launch_bounds__(256) void gemm_bt(const unsigned short* __restrict__ A,
                                               const unsigned short* __restrict__ W,
                                               const float* __restrict__ bias,
                                               void* __restrict__ outp,
                                               int M, int N, int K) {
  __shared__ unsigned short lA[128 * 32];
  __shared__ unsigned short lB[128 * 32];
  const int tid = threadIdx.x;
  const int wave = tid >> 6, lane = tid & 63;
  const int wm = wave >> 1, wn = wave & 1;
  const int g = lane >> 4, c = lane & 15;
  const int bm = blockIdx.x, bn = blockIdx.y;

  const int srow = lane >> 2;       // staging: row within 16-row wave chunk
  const int scol = (lane & 3) * 8;  // staging: bf16 col (8-elem groups)

  f32x4 acc[4][4] = {};

  const unsigned short* Abase = A + (long)(bm * 128) * K;
  const unsigned short* Wbase = W + (long)(bn * 128) * K;

  for (int k0 = 0; k0 < K; k0 += 32) {
    __syncthreads();  // protect LDS from previous iteration's readers
#pragma unroll
    for (int i = 0; i < 2; ++i) {
      const int row = i * 64 + wave * 16;  // wave-uniform chunk base
      gload_lds16(Abase + (long)(row + srow) * K + k0 + scol, lA + row * 32);
      gload_lds16(Wbase + (long)(row + srow) * K + k0 + scol, lB + row * 32);
    }
    __syncthreads();  // compiler emits vmcnt(0) drain before barrier

    short8 af[4], bf[4];
#pragma unroll
    for (int mi = 0; mi < 4; ++mi)
      af[mi] = *reinterpret_cast<const short8*>(&lA[(wm * 64 + mi * 16 + c) * 32 + g * 8]);
#pragma unroll
    for (int ni = 0; ni < 4; ++ni)
      bf[ni] = *reinterpret_cast<const short8*>(&lB[(wn * 64 + ni * 16 + c) * 32 + g * 8]);
#pragma unroll
    for (int mi = 0; mi < 4; ++mi)
#pragma unroll
      for (int ni = 0; ni < 4; ++ni)
        acc[mi][ni] =
            __builtin_amdgcn_mfma_f32_16x16x32_bf16(af[mi], bf[ni], acc[mi][ni], 0, 0, 0);
  }

  // epilogue: C row = bm*128 + wm*64 + mi*16 + g*4 + r ; col = bn*128 + wn*64 + ni*16 + c
#pragma unroll
  for (int mi = 0; mi < 4; ++mi) {
#pragma unroll
    for (int ni = 0; ni < 4; ++ni) {
      const int mg0 = bm * 128 + wm * 64 + mi * 16 + g * 4;
      const int ng = bn * 128 + wn * 64 + ni * 16 + c;
      const float bv = bias[ng];
#pragma unroll
      for (int r = 0; r < 4; ++r) {
        const int m = mg0 + r;
        float v = acc[mi][ni][r] + bv;
        if (MODE == 0) v *= 0.125f;  // fold 1/sqrt(d_k) into Q
        if (MODE == 0 || MODE == 1) {
          const int b_ = m >> 11, s_ = m & 2047, h_ = ng >> 6, d_ = ng & 63;
          ((unsigned short*)outp)[((long)(b_ * NH + h_) * S_LEN + s_) * DK + d_] = bf_round(v);
        } else if (MODE == 2) {
          const int b_ = m >> 11, s_ = m & 2047, h_ = ng >> 6, d_ = ng & 63;
          ((unsigned short*)outp)[((long)(b_ * NH + h_) * DK + d_) * S_LEN + s_] = bf_round(v);
        } else {
          ((float*)outp)[(long)m * N + ng] = v;
        }
      }
    }
  }
}

// ---------------- Flash attention, 32x32 MFMA, split-KV x2 ----------------
// Q: [BH][S][DK] bf16 (pre-scaled 1/8), K: [BH][S][DK] bf16, Vt: [BH][DK][S] bf16
// ctx out: [B][S][H*DK] bf16.
// Block = 4 waves = 2 q-tiles x 2 kv-halves; wave owns 32 q-rows x 1024 kv.
// Partial (m, l, acc) merged across the kv-halves via one LDS exchange.
// Swapped QK^T: st = mfma_32x32x16(K_frag, Q^T_frag) -> S^T[kv][q], q = lane&31.
// Grid 2048 blocks, XCD-chunked swizzle: each XCD gets 8 contiguous heads.
__global__ __launch_bounds__(256, 8) void attn_kernel(const unsigned short* __restrict__ Q,
                                                      const unsigned short* __restrict__ Kb,
                                                      const unsigned short* __restrict__ Vt,
                                                      unsigned short* __restrict__ ctx) {
  __shared__ float xlds[2][64][34];  // [qt][lane][cacc0(16) cacc1(16) m l]
  const int tid = threadIdx.x, wave = tid >> 6, lane = tid & 63;
  const int q = lane & 31;   // q column within wave tile; also K/V row selector
  const int h = lane >> 5;   // half-wave: owns k-slice h*8..h*8+7 of frags
  const int bid = blockIdx.x;
  const int swz = (bid & 7) * 256 + (bid >> 3);  // XCD-chunked remap (nwg=2048)
  const int hd = swz >> 5, qb = swz & 31;
  const int qt = wave & 1, kvh = wave >> 1;
  const int q0 = qb * 64 + qt * 32;

  const unsigned short* Qh = Q + (long)hd * S_LEN * DK;
  const unsigned short* Kh = Kb + (long)hd * S_LEN * DK;
  const unsigned short* Vh = Vt + (long)hd * DK * S_LEN;

  // Q^T B-frags, hoisted: lane holds Q[q0+q][d0*16 + h*8 + j]
  short8 qf[4];
#pragma unroll
  for (int d0 = 0; d0 < 4; ++d0)
    qf[d0] = *reinterpret_cast<const short8*>(&Qh[(long)(q0 + q) * DK + d0 * 16 + h * 8]);

  f32x16 cacc0 = {}, cacc1 = {};  // ctx^T: d-blocks [0..31], [32..63] x 32 q
  float mrun = -1e30f, lrun = 0.0f;

  const int kvB = kvh * (S_LEN / 2), kvE = kvB + S_LEN / 2;
  for (int kv0 = kvB; kv0 < kvE; kv0 += 32) {
    // ---- QK^T: S^T[32 kv][32 q] ----
    short8 kf[4];
#pragma unroll
    for (int d0 = 0; d0 < 4; ++d0)
      kf[d0] = *reinterpret_cast<const short8*>(&Kh[(long)(kv0 + q) * DK + d0 * 16 + h * 8]);
    f32x16 st = {};
#pragma unroll
    for (int d0 = 0; d0 < 4; ++d0)
      st = __builtin_amdgcn_mfma_f32_32x32x16_bf16(kf[d0], qf[d0], st, 0, 0, 0);
    // lane reg r: q col = q, kv = kv0 + (r&3) + 8*(r>>2) + 4*h

    // ---- online softmax (defer-max, THR=8) ----
    float t8[8];
#pragma unroll
    for (int r = 0; r < 8; ++r) t8[r] = fmaxf(st[r], st[r + 8]);
#pragma unroll
    for (int r = 0; r < 4; ++r) t8[r] = fmaxf(t8[r], t8[r + 4]);
    float pm = fmaxf(fmaxf(t8[0], t8[1]), fmaxf(t8[2], t8[3]));
    pm = fmaxf(pm, __shfl_xor(pm, 32));

    if (__any(pm > mrun + 8.0f)) {  // wave-uniform rescale branch
      const float mnew = fmaxf(mrun, pm);
      const float alpha = __expf(mrun - mnew);
      cacc0 *= alpha;
      cacc1 *= alpha;
      lrun *= alpha;
      mrun = mnew;
    }

    float p[16];
#pragma unroll
    for (int r = 0; r < 16; ++r) p[r] = __expf(st[r] - mrun);
    float s8[8];
#pragma unroll
    for (int r = 0; r < 8; ++r) s8[r] = p[r] + p[r + 8];
#pragma unroll
    for (int r = 0; r < 4; ++r) s8[r] = s8[r] + s8[r + 4];
    float ls = (s8[0] + s8[1]) + (s8[2] + s8[3]);
    ls += __shfl_xor(ls, 32);
    lrun += ls;

    // ---- pack P -> bf16 pairs ----
    unsigned pkA[4], pkB[4];
#pragma unroll
    for (int rq = 0; rq < 4; ++rq) {
      asm("v_cvt_pk_bf16_f32 %0, %1, %2" : "=v"(pkA[rq]) : "v"(p[4 * rq]), "v"(p[4 * rq + 1]));
      asm("v_cvt_pk_bf16_f32 %0, %1, %2" : "=v"(pkB[rq]) : "v"(p[4 * rq + 2]), "v"(p[4 * rq + 3]));
    }

    // ---- PV: ctx^T += V^T[d][kv] @ P^T[kv][q], two 16-kv steps ----
#pragma unroll
    for (int t = 0; t < 2; ++t) {
      unsigned sA = h ? pkA[2 * t] : pkA[2 * t + 1];
      unsigned sB = h ? pkB[2 * t] : pkB[2 * t + 1];
      unsigned rA = (unsigned)__shfl_xor((int)sA, 32);
      unsigned rB = (unsigned)__shfl_xor((int)sB, 32);
      union { unsigned w[4]; short8 v; } pf;
      pf.w[0] = h ? rA : pkA[2 * t];
      pf.w[1] = h ? rB : pkB[2 * t];
      pf.w[2] = h ? pkA[2 * t + 1] : rA;
      pf.w[3] = h ? pkB[2 * t + 1] : rB;
      short8 vf0 = *reinterpret_cast<const short8*>(
          &Vh[(long)(q) * S_LEN + kv0 + t * 16 + h * 8]);
      short8 vf1 = *reinterpret_cast<const short8*>(
          &Vh[(long)(32 + q) * S_LEN + kv0 + t * 16 + h * 8]);
      cacc0 = __builtin_amdgcn_mfma_f32_32x32x16_bf16(vf0, pf.v, cacc0, 0, 0, 0);
      cacc1 = __builtin_amdgcn_mfma_f32_32x32x16_bf16(vf1, pf.v, cacc1, 0, 0, 0);
    }
  }

  // ---- merge the two kv-halves (wave qt+2 -> wave qt) ----
  if (kvh) {
#pragma unroll
    for (int r = 0; r < 16; ++r) {
      xlds[qt][lane][r] = cacc0[r];
      xlds[qt][lane][16 + r] = cacc1[r];
    }
    xlds[qt][lane][32] = mrun;
    xlds[qt][lane][33] = lrun;
  }
  __syncthreads();
  if (kvh) return;

  const float m1 = xlds[qt][lane][32], l1 = xlds[qt][lane][33];
  const float mt = fmaxf(mrun, m1);
  float a0 = __expf(mrun - mt), a1 = __expf(m1 - mt);
  const float inv = 1.0f / (lrun * a0 + l1 * a1);
  a0 *= inv;
  a1 *= inv;

  // ---- epilogue: ctx^T[d][q] -> ctx[b][s=q0+q][h_*64 + d], d = db*32 + 8*rq + 4*h + rr ----
  const int b_ = hd >> 4, h_ = hd & 15;
  const long row = ((long)b_ * S_LEN + q0 + q) * DM + h_ * DK;
#pragma unroll
  for (int rq = 0; rq < 4; ++rq) {
    ushort4 w0, w1;
    w0.x = bf_round(cacc0[4 * rq + 0] * a0 + xlds[qt][lane][4 * rq + 0] * a1);
    w0.y = bf_round(cacc0[4 * rq + 1] * a0 + xlds[qt][lane][4 * rq + 1] * a1);
    w0.z = bf_round(cacc0[4 * rq + 2] * a0 + xlds[qt][lane][4 * rq + 2] * a1);
    w0.w = bf_round(cacc0[4 * rq + 3] * a0 + xlds[qt][lane][4 * rq + 3] * a1);
    w1.x = bf_round(cacc1[4 * rq + 0] * a0 + xlds[qt][lane][16 + 4 * rq + 0] * a1);
    w1.y = bf_round(cacc1[4 * rq + 1] * a0 + xlds[qt][lane][16 + 4 * rq + 1] * a1);
    w1.z = bf_round(cacc1[4 * rq + 2] * a0 + xlds[qt][lane][16 + 4 * rq + 2] * a1);
    w1.w = bf_round(cacc1[4 * rq + 3] * a0 + xlds[qt][lane][16 + 4 * rq + 3] * a1);
    *reinterpret_cast<ushort4*>(&ctx[row + 8 * rq + 4 * h]) = w0;
    *reinterpret_cast<ushort4*>(&ctx[row + 32 + 8 * rq + 4 * h]) = w1;
  }
}

extern "C" void kernel_launch(void* const* d_in, const int* in_sizes, int n_in,
                              void* d_out, int out_size, void* d_ws, size_t ws_size,
                              hipStream_t stream) {
  const float* X  = (const float*)d_in[0];
  const float* Wq = (const float*)d_in[1];
  const float* bq = (const float*)d_in[2];
  const float* Wk = (const float*)d_in[3];
  const float* bk = (const float*)d_in[4];
  const float* Wv = (const float*)d_in[5];
  const float* bv = (const float*)d_in[6];
  const float* Wo = (const float*)d_in[7];
  const float* bo = (const float*)d_in[8];

  char* ws = (char*)d_ws;
  const long MB = 1l << 20;
  unsigned short* Xbf = (unsigned short*)(ws + 0 * MB);   // 16 MB
  unsigned short* Ctx = Xbf;                              // alias: X dead after V GEMM
  unsigned short* Wqb = (unsigned short*)(ws + 16 * MB);  // 2 MB each
  unsigned short* Wkb = (unsigned short*)(ws + 18 * MB);
  unsigned short* Wvb = (unsigned short*)(ws + 20 * MB);
  unsigned short* Wob = (unsigned short*)(ws + 22 * MB);
  unsigned short* Qb  = (unsigned short*)(ws + 24 * MB);  // 16 MB
  unsigned short* Kbf = (unsigned short*)(ws + 40 * MB);  // 16 MB
  unsigned short* Vtb = (unsigned short*)(ws + 56 * MB);  // 16 MB, ends at 72 MB

  CvtArgs ca;
  ca.in[0] = X;  ca.out[0] = Xbf;
  ca.in[1] = Wq; ca.out[1] = Wqb;
  ca.in[2] = Wk; ca.out[2] = Wkb;
  ca.in[3] = Wv; ca.out[3] = Wvb;
  ca.in[4] = Wo; ca.out[4] = Wob;
  cvt_all<<<4096 + 4 * 512, 256, 0, stream>>>(ca);

  const dim3 gg(M_TOT / 128, DM / 128);
  gemm_bt<0><<<gg, 256, 0, stream>>>(Xbf, Wqb, bq, Qb, M_TOT, DM, DM);
  gemm_bt<1><<<gg, 256, 0, stream>>>(Xbf, Wkb, bk, Kbf, M_TOT, DM, DM);
  gemm_bt<2><<<gg, 256, 0, stream>>>(Xbf, Wvb, bv, Vtb, M_TOT, DM, DM);

  attn_kernel<<<dim3(2048), 256, 0, stream>>>(Qb, Kbf, Vtb, Ctx);

  gemm_bt<3><<<gg, 256, 0, stream>>>(Ctx, Wob, bo, d_out, M_TOT, DM, DM);
}

// Round 4
// 343.491 us; speedup vs baseline: 1.7719x; 1.7719x over previous
//
#include <hip/hip_runtime.h>
#include <hip/hip_bf16.h>
#include <stdint.h>

#define DEV_INLINE __device__ __forceinline__

typedef __attribute__((ext_vector_type(4))) float f32x4;
typedef __attribute__((ext_vector_type(16))) float f32x16;
typedef __attribute__((ext_vector_type(8))) short short8;

static constexpr int S_LEN = 2048;
static constexpr int DM = 1024;
static constexpr int NH = 16;
static constexpr int DK = 64;
static constexpr int BATCH = 4;
static constexpr int M_TOT = BATCH * S_LEN;  // 8192

// Q pre-scale: (1/sqrt(64)) * log2(e) so softmax runs in exp2 domain.
#define QSCALE 0.18033688011112042f

DEV_INLINE unsigned short bf_round(float x) {
  unsigned u = __builtin_bit_cast(unsigned, x);
  u += 0x7fffu + ((u >> 16) & 1u);
  return (unsigned short)(u >> 16);
}

// ---------------- fp32 -> bf16 convert, all 5 tensors in one dispatch ----------------
struct CvtArgs {
  const float* in[5];
  unsigned short* out[5];
};
__global__ __launch_bounds__(256) void cvt_all(CvtArgs a) {
  int bid = blockIdx.x;
  int which, base;
  if (bid < 4096) { which = 0; base = bid; }
  else { int r = bid - 4096; which = 1 + (r >> 9); base = r & 511; }
  const float* __restrict__ in = a.in[which];
  unsigned short* __restrict__ out = a.out[which];
  long i = ((long)base * 256 + threadIdx.x) * 8;
  float4 va = *reinterpret_cast<const float4*>(in + i);
  float4 vb = *reinterpret_cast<const float4*>(in + i + 4);
  union { unsigned short u[8]; uint4 v; } pk;
  pk.u[0] = bf_round(va.x); pk.u[1] = bf_round(va.y);
  pk.u[2] = bf_round(va.z); pk.u[3] = bf_round(va.w);
  pk.u[4] = bf_round(vb.x); pk.u[5] = bf_round(vb.y);
  pk.u[6] = bf_round(vb.z); pk.u[7] = bf_round(vb.w);
  *reinterpret_cast<uint4*>(out + i) = pk.v;
}

// ---------------- async global->LDS 16B ----------------
DEV_INLINE void gload_lds16(const unsigned short* g, unsigned short* l) {
  __builtin_amdgcn_global_load_lds(
      (const __attribute__((address_space(1))) unsigned int*)g,
      (__attribute__((address_space(3))) unsigned int*)l,
      16, 0, 0);
}

// ---------------- fused QKV GEMM ----------------
// C[m][n] = sum_k A[m,k] * W[n,k] + bias[n]; blockIdx.z selects {Q,K,V}.
// z=0: Q epilogue (scale QSCALE, bf16 -> [BH][S][DK])
// z=1: K epilogue (bf16 -> [BH][S][DK])
// z=2: V epilogue (bf16 -> transposed [BH][DK][S])
struct QkvArgs {
  const unsigned short* W[3];
  const float* bias[3];
  unsigned short* out[3];
};
__global__ __launch_bounds__(256) void gemm_qkv(const unsigned short* __restrict__ A,
                                                QkvArgs args) {
  constexpr int K = DM, N = DM;
  __shared__ unsigned short lA[128 * 32];
  __shared__ unsigned short lB[128 * 32];
  const int tid = threadIdx.x;
  const int wave = tid >> 6, lane = tid & 63;
  const int wm = wave >> 1, wn = wave & 1;
  const int g = lane >> 4, c = lane & 15;
  const int bm = blockIdx.x, bn = blockIdx.y, z = blockIdx.z;

  const unsigned short* __restrict__ W = args.W[z];
  const float* __restrict__ bias = args.bias[z];
  unsigned short* __restrict__ outp = args.out[z];

  const int srow = lane >> 2;
  const int scol = (lane & 3) * 8;

  f32x4 acc[4][4] = {};

  const unsigned short* Abase = A + (long)(bm * 128) * K;
  const unsigned short* Wbase = W + (long)(bn * 128) * K;

  for (int k0 = 0; k0 < K; k0 += 32) {
    __syncthreads();
#pragma unroll
    for (int i = 0; i < 2; ++i) {
      const int row = i * 64 + wave * 16;
      gload_lds16(Abase + (long)(row + srow) * K + k0 + scol, lA + row * 32);
      gload_lds16(Wbase + (long)(row + srow) * K + k0 + scol, lB + row * 32);
    }
    __syncthreads();

    short8 af[4], bf[4];
#pragma unroll
    for (int mi = 0; mi < 4; ++mi)
      af[mi] = *reinterpret_cast<const short8*>(&lA[(wm * 64 + mi * 16 + c) * 32 + g * 8]);
#pragma unroll
    for (int ni = 0; ni < 4; ++ni)
      bf[ni] = *reinterpret_cast<const short8*>(&lB[(wn * 64 + ni * 16 + c) * 32 + g * 8]);
#pragma unroll
    for (int mi = 0; mi < 4; ++mi)
#pragma unroll
      for (int ni = 0; ni < 4; ++ni)
        acc[mi][ni] =
            __builtin_amdgcn_mfma_f32_16x16x32_bf16(af[mi], bf[ni], acc[mi][ni], 0, 0, 0);
  }

#pragma unroll
  for (int mi = 0; mi < 4; ++mi) {
#pragma unroll
    for (int ni = 0; ni < 4; ++ni) {
      const int mg0 = bm * 128 + wm * 64 + mi * 16 + g * 4;
      const int ng = bn * 128 + wn * 64 + ni * 16 + c;
      const float bv = bias[ng];
#pragma unroll
      for (int r = 0; r < 4; ++r) {
        const int m = mg0 + r;
        float v = acc[mi][ni][r] + bv;
        if (z == 0) v *= QSCALE;
        const int b_ = m >> 11, s_ = m & 2047, h_ = ng >> 6, d_ = ng & 63;
        if (z < 2) {
          outp[((long)(b_ * NH + h_) * S_LEN + s_) * DK + d_] = bf_round(v);
        } else {
          outp[((long)(b_ * NH + h_) * DK + d_) * S_LEN + s_] = bf_round(v);
        }
      }
    }
  }
}

// ---------------- output-projection GEMM (fp32 out) ----------------
__global__ __launch_bounds__(256) void gemm_out(const unsigned short* __restrict__ A,
                                                const unsigned short* __restrict__ W,
                                                const float* __restrict__ bias,
                                                float* __restrict__ outp) {
  constexpr int K = DM, N = DM;
  __shared__ unsigned short lA[128 * 32];
  __shared__ unsigned short lB[128 * 32];
  const int tid = threadIdx.x;
  const int wave = tid >> 6, lane = tid & 63;
  const int wm = wave >> 1, wn = wave & 1;
  const int g = lane >> 4, c = lane & 15;
  const int bm = blockIdx.x, bn = blockIdx.y;

  const int srow = lane >> 2;
  const int scol = (lane & 3) * 8;

  f32x4 acc[4][4] = {};

  const unsigned short* Abase = A + (long)(bm * 128) * K;
  const unsigned short* Wbase = W + (long)(bn * 128) * K;

  for (int k0 = 0; k0 < K; k0 += 32) {
    __syncthreads();
#pragma unroll
    for (int i = 0; i < 2; ++i) {
      const int row = i * 64 + wave * 16;
      gload_lds16(Abase + (long)(row + srow) * K + k0 + scol, lA + row * 32);
      gload_lds16(Wbase + (long)(row + srow) * K + k0 + scol, lB + row * 32);
    }
    __syncthreads();

    short8 af[4], bf[4];
#pragma unroll
    for (int mi = 0; mi < 4; ++mi)
      af[mi] = *reinterpret_cast<const short8*>(&lA[(wm * 64 + mi * 16 + c) * 32 + g * 8]);
#pragma unroll
    for (int ni = 0; ni < 4; ++ni)
      bf[ni] = *reinterpret_cast<const short8*>(&lB[(wn * 64 + ni * 16 + c) * 32 + g * 8]);
#pragma unroll
    for (int mi = 0; mi < 4; ++mi)
#pragma unroll
      for (int ni = 0; ni < 4; ++ni)
        acc[mi][ni] =
            __builtin_amdgcn_mfma_f32_16x16x32_bf16(af[mi], bf[ni], acc[mi][ni], 0, 0, 0);
  }

#pragma unroll
  for (int mi = 0; mi < 4; ++mi) {
#pragma unroll
    for (int ni = 0; ni < 4; ++ni) {
      const int mg0 = bm * 128 + wm * 64 + mi * 16 + g * 4;
      const int ng = bn * 128 + wn * 64 + ni * 16 + c;
      const float bv = bias[ng];
#pragma unroll
      for (int r = 0; r < 4; ++r)
        outp[(long)(mg0 + r) * N + ng] = acc[mi][ni][r] + bv;
    }
  }
}

// ---------------- Flash attention, 32x32 MFMA, software-pipelined ----------------
// Q: [BH][S][DK] bf16 (pre-scaled QSCALE), K: [BH][S][DK] bf16, Vt: [BH][DK][S] bf16
// ctx out: [B][S][H*DK] bf16.
// Block = 4 waves; wave owns 32 q-rows x full KV (no LDS, no barriers).
// Pipeline: K(t+1) + V(t) loads issue BEFORE the softmax chain of t.
// Softmax in exp2 domain (log2e folded into Q scale).
// XCD-chunked swizzle: each XCD gets 128 contiguous blocks = 8 whole heads.
__global__ __launch_bounds__(256, 4) void attn_kernel(const unsigned short* __restrict__ Q,
                                                      const unsigned short* __restrict__ Kb,
                                                      const unsigned short* __restrict__ Vt,
                                                      unsigned short* __restrict__ ctx) {
  const int tid = threadIdx.x, wave = tid >> 6, lane = tid & 63;
  const int q = lane & 31;   // q column; also K/V row selector
  const int h = lane >> 5;   // half-wave: owns k-slice h*8..h*8+7 of frags
  const int bid = blockIdx.x;
  const int swz = (bid & 7) * 128 + (bid >> 3);  // nwg=1024, 8 XCDs, bijective
  const int hd = swz >> 4, qb = swz & 15;
  const int q0 = qb * 128 + wave * 32;

  const unsigned short* Qh = Q + (long)hd * S_LEN * DK;
  const unsigned short* Kh = Kb + (long)hd * S_LEN * DK;
  const unsigned short* Vh = Vt + (long)hd * DK * S_LEN;

  // lane-resolved base pointers
  const unsigned short* Kq = Kh + (long)q * DK + h * 8;          // + kv*DK + d0*16
  const unsigned short* Vq0 = Vh + (long)q * S_LEN + h * 8;      // d rows 0..31
  const unsigned short* Vq1 = Vh + (long)(32 + q) * S_LEN + h * 8;

  short8 qf[4];
#pragma unroll
  for (int d0 = 0; d0 < 4; ++d0)
    qf[d0] = *reinterpret_cast<const short8*>(&Qh[(long)(q0 + q) * DK + d0 * 16 + h * 8]);

  f32x16 cacc0 = {}, cacc1 = {};  // ctx^T: d-blocks [0..31], [32..63] x 32 q
  float mrun = -1e30f, lrun = 0.0f;

  // prologue: K frags for kv0 = 0
  short8 kf[4];
#pragma unroll
  for (int d0 = 0; d0 < 4; ++d0)
    kf[d0] = *reinterpret_cast<const short8*>(Kq + d0 * 16);

  for (int kv0 = 0; kv0 < S_LEN; kv0 += 32) {
    // ---- prefetch next K tile (wraps harmlessly on last iter) ----
    const int kvn = (kv0 + 32) & (S_LEN - 1);
    short8 kn[4];
#pragma unroll
    for (int d0 = 0; d0 < 4; ++d0)
      kn[d0] = *reinterpret_cast<const short8*>(Kq + (long)kvn * DK + d0 * 16);
    // ---- prefetch V for this tile ----
    short8 vf[4];
    vf[0] = *reinterpret_cast<const short8*>(Vq0 + kv0);
    vf[1] = *reinterpret_cast<const short8*>(Vq1 + kv0);
    vf[2] = *reinterpret_cast<const short8*>(Vq0 + kv0 + 16);
    vf[3] = *reinterpret_cast<const short8*>(Vq1 + kv0 + 16);

    // ---- QK^T: S^T[32 kv][32 q] (exp2 domain) ----
    f32x16 st = {};
#pragma unroll
    for (int d0 = 0; d0 < 4; ++d0)
      st = __builtin_amdgcn_mfma_f32_32x32x16_bf16(kf[d0], qf[d0], st, 0, 0, 0);
    // lane reg r: q col = q, kv = kv0 + (r&3) + 8*(r>>2) + 4*h

    // ---- online softmax (defer-max, THR=8 in log2 units) ----
    float t8[8];
#pragma unroll
    for (int r = 0; r < 8; ++r) t8[r] = fmaxf(st[r], st[r + 8]);
#pragma unroll
    for (int r = 0; r < 4; ++r) t8[r] = fmaxf(t8[r], t8[r + 4]);
    float pm = fmaxf(fmaxf(t8[0], t8[1]), fmaxf(t8[2], t8[3]));
    pm = fmaxf(pm, __shfl_xor(pm, 32));

    if (__any(pm > mrun + 8.0f)) {  // wave-uniform rescale branch
      const float mnew = fmaxf(mrun, pm);
      const float alpha = __builtin_amdgcn_exp2f(mrun - mnew);
      cacc0 *= alpha;
      cacc1 *= alpha;
      lrun *= alpha;
      mrun = mnew;
    }

    float p[16];
#pragma unroll
    for (int r = 0; r < 16; ++r) p[r] = __builtin_amdgcn_exp2f(st[r] - mrun);
    float s8[8];
#pragma unroll
    for (int r = 0; r < 8; ++r) s8[r] = p[r] + p[r + 8];
#pragma unroll
    for (int r = 0; r < 4; ++r) s8[r] = s8[r] + s8[r + 4];
    float ls = (s8[0] + s8[1]) + (s8[2] + s8[3]);
    ls += __shfl_xor(ls, 32);
    lrun += ls;

    // ---- pack P -> bf16 pairs ----
    unsigned pkA[4], pkB[4];
#pragma unroll
    for (int rq = 0; rq < 4; ++rq) {
      asm("v_cvt_pk_bf16_f32 %0, %1, %2" : "=v"(pkA[rq]) : "v"(p[4 * rq]), "v"(p[4 * rq + 1]));
      asm("v_cvt_pk_bf16_f32 %0, %1, %2" : "=v"(pkB[rq]) : "v"(p[4 * rq + 2]), "v"(p[4 * rq + 3]));
    }

    // ---- PV: ctx^T += V^T[d][kv] @ P^T[kv][q], two 16-kv steps ----
#pragma unroll
    for (int t = 0; t < 2; ++t) {
      unsigned sA = h ? pkA[2 * t] : pkA[2 * t + 1];
      unsigned sB = h ? pkB[2 * t] : pkB[2 * t + 1];
      unsigned rA = (unsigned)__shfl_xor((int)sA, 32);
      unsigned rB = (unsigned)__shfl_xor((int)sB, 32);
      union { unsigned w[4]; short8 v; } pf;
      pf.w[0] = h ? rA : pkA[2 * t];
      pf.w[1] = h ? rB : pkB[2 * t];
      pf.w[2] = h ? pkA[2 * t + 1] : rA;
      pf.w[3] = h ? pkB[2 * t + 1] : rB;
      cacc0 = __builtin_amdgcn_mfma_f32_32x32x16_bf16(vf[2 * t], pf.v, cacc0, 0, 0, 0);
      cacc1 = __builtin_amdgcn_mfma_f32_32x32x16_bf16(vf[2 * t + 1], pf.v, cacc1, 0, 0, 0);
    }

    // ---- rotate pipeline ----
#pragma unroll
    for (int d0 = 0; d0 < 4; ++d0) kf[d0] = kn[d0];
  }

  // ---- epilogue: ctx^T[d][q] -> ctx[b][s=q0+q][h_*64 + d], d = db*32 + 8*rq + 4*h + rr ----
  const float inv = 1.0f / lrun;
  const int b_ = hd >> 4, h_ = hd & 15;
  const long row = ((long)b_ * S_LEN + q0 + q) * DM + h_ * DK;
#pragma unroll
  for (int rq = 0; rq < 4; ++rq) {
    ushort4 w0, w1;
    w0.x = bf_round(cacc0[4 * rq + 0] * inv);
    w0.y = bf_round(cacc0[4 * rq + 1] * inv);
    w0.z = bf_round(cacc0[4 * rq + 2] * inv);
    w0.w = bf_round(cacc0[4 * rq + 3] * inv);
    w1.x = bf_round(cacc1[4 * rq + 0] * inv);
    w1.y = bf_round(cacc1[4 * rq + 1] * inv);
    w1.z = bf_round(cacc1[4 * rq + 2] * inv);
    w1.w = bf_round(cacc1[4 * rq + 3] * inv);
    *reinterpret_cast<ushort4*>(&ctx[row + 8 * rq + 4 * h]) = w0;
    *reinterpret_cast<ushort4*>(&ctx[row + 32 + 8 * rq + 4 * h]) = w1;
  }
}

extern "C" void kernel_launch(void* const* d_in, const int* in_sizes, int n_in,
                              void* d_out, int out_size, void* d_ws, size_t ws_size,
                              hipStream_t stream) {
  const float* X  = (const float*)d_in[0];
  const float* Wq = (const float*)d_in[1];
  const float* bq = (const float*)d_in[2];
  const float* Wk = (const float*)d_in[3];
  const float* bk = (const float*)d_in[4];
  const float* Wv = (const float*)d_in[5];
  const float* bv = (const float*)d_in[6];
  const float* Wo = (const float*)d_in[7];
  const float* bo = (const float*)d_in[8];

  char* ws = (char*)d_ws;
  const long MB = 1l << 20;
  unsigned short* Xbf = (unsigned short*)(ws + 0 * MB);   // 16 MB
  unsigned short* Ctx = Xbf;                              // alias: X dead after V GEMM
  unsigned short* Wqb = (unsigned short*)(ws + 16 * MB);  // 2 MB each
  unsigned short* Wkb = (unsigned short*)(ws + 18 * MB);
  unsigned short* Wvb = (unsigned short*)(ws + 20 * MB);
  unsigned short* Wob = (unsigned short*)(ws + 22 * MB);
  unsigned short* Qb  = (unsigned short*)(ws + 24 * MB);  // 16 MB
  unsigned short* Kbf = (unsigned short*)(ws + 40 * MB);  // 16 MB
  unsigned short* Vtb = (unsigned short*)(ws + 56 * MB);  // 16 MB, ends at 72 MB

  CvtArgs ca;
  ca.in[0] = X;  ca.out[0] = Xbf;
  ca.in[1] = Wq; ca.out[1] = Wqb;
  ca.in[2] = Wk; ca.out[2] = Wkb;
  ca.in[3] = Wv; ca.out[3] = Wvb;
  ca.in[4] = Wo; ca.out[4] = Wob;
  cvt_all<<<4096 + 4 * 512, 256, 0, stream>>>(ca);

  QkvArgs qa;
  qa.W[0] = Wqb; qa.bias[0] = bq; qa.out[0] = Qb;
  qa.W[1] = Wkb; qa.bias[1] = bk; qa.out[1] = Kbf;
  qa.W[2] = Wvb; qa.bias[2] = bv; qa.out[2] = Vtb;
  gemm_qkv<<<dim3(M_TOT / 128, DM / 128, 3), 256, 0, stream>>>(Xbf, qa);

  attn_kernel<<<dim3(1024), 256, 0, stream>>>(Qb, Kbf, Vtb, Ctx);

  gemm_out<<<dim3(M_TOT / 128, DM / 128), 256, 0, stream>>>(Ctx, Wob, bo, (float*)d_out);
}